// Round 16
// baseline (227.064 us; speedup 1.0000x reference)
//
#include <hip/hip_runtime.h>
#include <hip/hip_bf16.h>
#include <math.h>

// Problem constants (reference: B,S,D,H,FD = 2,2048,1024,16,64; DK=64, ALPHA=1)
#define Bb 2
#define Ss 2048
#define Dd 1024
#define Hh 16
#define DK 64
#define FD 64

#define LOG2E 1.4426950408889634f

typedef short short8 __attribute__((ext_vector_type(8)));   // 8 bf16 (4 VGPRs)
typedef float f32x4 __attribute__((ext_vector_type(4)));
typedef unsigned int u32;

static __device__ inline ushort f2bf(float f) {
    union { float f; unsigned u; } v; v.f = f;
    unsigned r = v.u + 0x7FFF + ((v.u >> 16) & 1);   // round-to-nearest-even
    return (ushort)(r >> 16);
}

// packed f32x2 -> bf16x2 RNE in one VALU op
static __device__ inline uint cvt_pk_bf16(float lo, float hi) {
    uint r;
    asm("v_cvt_pk_bf16_f32 %0, %1, %2" : "=v"(r) : "v"(lo), "v"(hi));
    return r;
}
static __device__ inline float fexp2(float x) {
    return __builtin_amdgcn_exp2f(x);   // v_exp_f32: D = 2^S0
}

// async global->LDS, 16B per lane; LDS dest is wave-uniform base + lane*16
static __device__ inline void gload_lds16(const ushort* g, ushort* l) {
    __builtin_amdgcn_global_load_lds((const __attribute__((address_space(1))) u32*)g,
                                     (__attribute__((address_space(3))) u32*)l, 16, 0, 0);
}

// ---------------------------------------------------------------------------
// prep: fused cast_bf16 | transpose_cast4 | (l2norm + pack_aux) in ONE launch
// (round-13 VERIFIED).
// ---------------------------------------------------------------------------
__global__ __launch_bounds__(256) void prep(const float* __restrict__ x,
                                            const float* __restrict__ features,
                                            const float* __restrict__ requirements,
                                            const float* __restrict__ W0,
                                            const float* __restrict__ W1,
                                            const float* __restrict__ W2,
                                            const float* __restrict__ W3,
                                            ushort* __restrict__ WT,
                                            ushort* __restrict__ xb,
                                            ushort* __restrict__ Qext,
                                            ushort* __restrict__ Kext) {
    __shared__ float T[64][65];
    const int blk = blockIdx.x;
    const int tid = threadIdx.x;

    if (blk < 8192) {
        // ---- cast fp32 -> bf16 (2 elems/thread) ----
        size_t p = (size_t)blk * 256 + tid;
        float2 v = *(const float2*)(x + 2 * p);
        ((uint*)xb)[p] = (uint)f2bf(v.x) | ((uint)f2bf(v.y) << 16);
        return;
    }
    if (blk < 9216) {
        // ---- transpose+cast weights (was dim3(16,16,4)) ----
        const int f = blk - 8192;
        const int bx = f & 15, by = (f >> 4) & 15, bz = f >> 8;
        const float* W = bz == 0 ? W0 : bz == 1 ? W1 : bz == 2 ? W2 : W3;
        ushort* dst = WT + (size_t)bz * Dd * Dd;
        const int k0 = bx * 64, n0 = by * 64;
#pragma unroll
        for (int i = 0; i < 4; ++i) {
            int kr = i * 16 + (tid >> 4);
            int nc = (tid & 15) * 4;
            float4 v = *(const float4*)(W + (size_t)(k0 + kr) * Dd + n0 + nc);
            T[kr][nc] = v.x; T[kr][nc + 1] = v.y; T[kr][nc + 2] = v.z; T[kr][nc + 3] = v.w;
        }
        __syncthreads();
        int nr = tid >> 2;
        int kc = (tid & 3) * 16;
        uint pk[8];
#pragma unroll
        for (int j = 0; j < 8; ++j)
            pk[j] = (uint)f2bf(T[kc + 2 * j][nr]) | ((uint)f2bf(T[kc + 2 * j + 1][nr]) << 16);
        uint* o = (uint*)(dst + (size_t)(n0 + nr) * Dd + k0 + kc);
        *(int4*)o = *(int4*)&pk[0];
        *(int4*)(o + 4) = *(int4*)&pk[4];
        return;
    }
    // ---- fused l2norm + aux pack: 4 rows/block, wave per row ----
    {
        const int f3 = blk - 9216;               // 0..1023
        const int row = f3 * 4 + (tid >> 6);     // 0..4095 = b*S + s
        const int lane = tid & 63;
        const int b = row >> 11, s = row & (Ss - 1);
        // lanes 0-31: features pairs (-> Kext aux); lanes 32-63: requirements
        const int j = lane & 31;
        const float* src = (lane < 32) ? features : requirements;
        float2 v = *(const float2*)(src + (size_t)row * FD + 2 * j);
        float ss = v.x * v.x + v.y * v.y;
#pragma unroll
        for (int off = 16; off; off >>= 1) ss += __shfl_xor(ss, off, 64);  // per-half
        const float inv = 1.0f / fmaxf(sqrtf(ss), 1e-12f);
        const float scl = (lane < 32) ? inv : inv * LOG2E;
        const uint pk = cvt_pk_bf16(v.x * scl, v.y * scl);
        uint* dstq = (uint*)Qext;
        uint* dstk = (uint*)Kext;
#pragma unroll
        for (int h = 0; h < 16; ++h) {
            size_t rowq = ((size_t)(b * Hh + h) * Ss + s) * 64 + 32 + j;
            if (lane < 32) dstk[rowq] = pk;
            else           dstq[rowq] = pk;
        }
    }
}

// ---------------------------------------------------------------------------
// Fused QKV bf16 MFMA GEMM. 128x128 tile, BK=64, 4 waves.
// Round-15 VERIFIED: gload_lds staging + XCD swizzle + [136] epilogue +
// fused V^T write (pack_vt eliminated).
// id0 -> Qext (x 0.125*log2e), id1 -> Kext, id2 -> Vt (transposed).
// ---------------------------------------------------------------------------
__global__ __launch_bounds__(256) void gemm_qkv(const ushort* __restrict__ xb,
                                                const ushort* __restrict__ WT,
                                                const float* __restrict__ bq,
                                                const float* __restrict__ bk,
                                                const float* __restrict__ bv,
                                                ushort* __restrict__ Qext,
                                                ushort* __restrict__ Kext,
                                                ushort* __restrict__ Vt) {
    __shared__ ushort smem[17408];        // 34.8KB: As|Bs (32KB) main, Ep epi
    ushort (*As)[64] = (ushort (*)[64])smem;            // [128][64]
    ushort (*Bs)[64] = (ushort (*)[64])(smem + 8192);   // [128][64]
    const int tid = threadIdx.x;
    const int lane = tid & 63, wave = tid >> 6;
    const int col = lane & 15, quad = lane >> 4;
    const int wm = wave >> 1, wn = wave & 1;
    // XCD swizzle (bijective): flat -> (id, n0=xcd*128, m0)
    const int flat = blockIdx.x + 24 * blockIdx.y;
    const int xcd = flat & 7;
    const int jj = flat >> 3;                     // 0..95
    const int id = jj % 3;                        // 0:Q 1:K 2:V
    const int n0 = xcd * 128;
    const int m0 = (jj / 3) * 128;
    const ushort* BTw = WT + (size_t)id * Dd * Dd;
    const float* bias = id == 0 ? bq : id == 1 ? bk : bv;

    const int l8 = lane >> 3;
    const int srcg = (lane & 7) ^ l8;             // r&7 == lane>>3
    const ushort* aS[4]; const ushort* bS[4];
    ushort* aD[4]; ushort* bD[4];
#pragma unroll
    for (int i = 0; i < 4; ++i) {
        int r = wave * 32 + i * 8 + l8;
        aS[i] = xb  + (size_t)(m0 + r) * Dd + srcg * 8;
        bS[i] = BTw + (size_t)(n0 + r) * Dd + srcg * 8;
        aD[i] = smem + (wave * 4 + i) * 512;
        bD[i] = smem + 8192 + (wave * 4 + i) * 512;
    }
    const int xs = col & 7;

    f32x4 acc[4][4] = {};

    for (int k0 = 0; k0 < Dd; k0 += 64) {
        __syncthreads();
#pragma unroll
        for (int i = 0; i < 4; ++i) {
            gload_lds16(aS[i] + k0, aD[i]);
            gload_lds16(bS[i] + k0, bD[i]);
        }
        __syncthreads();
#pragma unroll
        for (int kk = 0; kk < 2; ++kk) {
            short8 af[4], bf[4];
#pragma unroll
            for (int i = 0; i < 4; ++i) {
                af[i] = *(const short8*)&As[wm * 64 + i * 16 + col][((kk * 4 + quad) ^ xs) * 8];
                bf[i] = *(const short8*)&Bs[wn * 64 + i * 16 + col][((kk * 4 + quad) ^ xs) * 8];
            }
#pragma unroll
            for (int i = 0; i < 4; ++i)
#pragma unroll
                for (int j = 0; j < 4; ++j)
                    acc[i][j] = __builtin_amdgcn_mfma_f32_16x16x32_bf16(af[i], bf[j], acc[i][j], 0, 0, 0);
        }
    }

    // ---- coalesced epilogue via LDS (v8-verified, [136] padded) ----
    __syncthreads();                               // As/Bs reads all done
    ushort (*Ep)[136] = (ushort (*)[136])smem;     // 128x136 = 34.8KB
    const float scl = (id == 0) ? 0.125f * LOG2E : 1.0f;
#pragma unroll
    for (int j = 0; j < 4; ++j) {
        int n_local = wn * 64 + j * 16 + col;
        float bvl = bias[n0 + n_local];
#pragma unroll
        for (int i = 0; i < 4; ++i) {
            int mb = wm * 64 + i * 16 + quad * 4;
#pragma unroll
            for (int reg = 0; reg < 4; ++reg)
                Ep[mb + reg][n_local] = f2bf((acc[i][j][reg] + bvl) * scl);
        }
    }
    __syncthreads();
    if (id == 2) {
        // ---- fused V^T write: Vt[(b*Hh+hh)*64+d][s0 + 2*lane(+1)] ----
        const int b = m0 >> 11, s0 = m0 & (Ss - 1);
#pragma unroll
        for (int it = 0; it < 32; ++it) {
            int n_local = wave * 32 + it;        // waves 0-1: head 0; 2-3: head 1
            int hh = (n0 >> 6) + (n_local >> 6);
            int d = n_local & 63;
            uint pk = (uint)Ep[lane * 2][n_local] | ((uint)Ep[lane * 2 + 1][n_local] << 16);
            uint* dst = (uint*)(Vt + ((size_t)((b * Hh + hh) * DK + d)) * Ss + s0);
            dst[lane] = pk;                      // 64 lanes -> 256B coalesced
        }
    } else {
        const int mrow = tid >> 1;               // 0..127 local s
        const int half = tid & 1;                // which head of the 2 in n-range
        const int b = m0 >> 11, s = (m0 & (Ss - 1)) + mrow;
        const int hh = (n0 >> 6) + half;
        ushort* drow = (id == 0 ? Qext : Kext) + ((size_t)(b * Hh + hh) * Ss + s) * 128;
#pragma unroll
        for (int k = 0; k < 8; ++k)
            *(int4*)(drow + k * 8) = *(int4*)&Ep[mrow][half * 64 + k * 8];
    }
}

// ---------------------------------------------------------------------------
// Output projection: out[M][N] f32 = abb(bf16) @ WoT + bo.
// NEW: 512 threads / 8 waves per 128x128 tile (was 4). Grid (8,32) = 256
// blocks = 1 block/CU; 8 waves/CU halves the exposed per-K-step drain
// (gemm_out was the only kernel at 4 waves/CU — v11's measured pathology).
// Wave w owns a 32x64 sub-tile; staging uses the attn-v12-verified granule
// algebra (1024 granules/matrix, source-XOR swizzle, linear dest).
// Accumulation order per output element unchanged -> bit-identical.
// ---------------------------------------------------------------------------
__global__ __launch_bounds__(512) void gemm_out(const ushort* __restrict__ Ab,
                                                const ushort* __restrict__ BT,
                                                const float* __restrict__ bias,
                                                float* __restrict__ C) {
    __shared__ ushort As[128][64];
    __shared__ ushort Bs[128][64];
    const int tid = threadIdx.x;
    const int lane = tid & 63, wave = tid >> 6;   // 0..7
    const int col = lane & 15, quad = lane >> 4;
    const int wm = wave >> 1;                     // 0..3: 32-row band
    const int wn = wave & 1;                      // 0..1: 64-col band
    const int n0 = blockIdx.x * 128;
    const int m0 = blockIdx.y * 128;

    // staging: 1024 granules per matrix = 2 insts x 512 threads.
    // LDS[r][g] = global[r][g ^ (r&7)]; dest linear, wave-uniform base.
    const ushort* aS[2]; const ushort* bS[2];
    ushort* aD[2]; ushort* bD[2];
#pragma unroll
    for (int i = 0; i < 2; ++i) {
        int G = i * 512 + tid;                    // granule index 0..1023
        int r = G >> 3, g = G & 7;
        aS[i] = Ab + (size_t)(m0 + r) * Dd + ((g ^ (r & 7)) * 8);
        bS[i] = BT + (size_t)(n0 + r) * Dd + ((g ^ (r & 7)) * 8);
        aD[i] = &As[0][0] + (i * 512 + wave * 64) * 8;
        bD[i] = &Bs[0][0] + (i * 512 + wave * 64) * 8;
    }
    const int xs = col & 7;

    f32x4 acc[2][4] = {};

    for (int k0 = 0; k0 < Dd; k0 += 64) {
        __syncthreads();
#pragma unroll
        for (int i = 0; i < 2; ++i) {
            gload_lds16(aS[i] + k0, aD[i]);
            gload_lds16(bS[i] + k0, bD[i]);
        }
        __syncthreads();
#pragma unroll
        for (int kk = 0; kk < 2; ++kk) {
            short8 af[2], bf[4];
#pragma unroll
            for (int i = 0; i < 2; ++i)
                af[i] = *(const short8*)&As[wm * 32 + i * 16 + col][((kk * 4 + quad) ^ xs) * 8];
#pragma unroll
            for (int j = 0; j < 4; ++j)
                bf[j] = *(const short8*)&Bs[wn * 64 + j * 16 + col][((kk * 4 + quad) ^ xs) * 8];
#pragma unroll
            for (int i = 0; i < 2; ++i)
#pragma unroll
                for (int j = 0; j < 4; ++j)
                    acc[i][j] = __builtin_amdgcn_mfma_f32_16x16x32_bf16(af[i], bf[j], acc[i][j], 0, 0, 0);
        }
    }

#pragma unroll
    for (int j = 0; j < 4; ++j) {
        int n = n0 + wn * 64 + j * 16 + col;
        float bvl = bias[n];
#pragma unroll
        for (int i = 0; i < 2; ++i) {
#pragma unroll
            for (int reg = 0; reg < 4; ++reg) {
                int m = m0 + wm * 32 + i * 16 + quad * 4 + reg;
                C[(size_t)m * Dd + n] = acc[i][j][reg] + bvl;
            }
        }
    }
}

// ---------------------------------------------------------------------------
// Flash attention v14 (round-11/14/15 VERIFIED, ~58 µs): 8 waves x 16-row
// strips, 40KB LDS, 64-key stages, gload_lds staging, two barriers/stage.
// XCD-aware balanced decode: id&7 = bh&7 (4 heads/XCD, L2-resident);
// co-resident pairs (id, id+256) share bh with qt-sums = 15.
// ---------------------------------------------------------------------------
#define ABQ 128

__global__ __launch_bounds__(512) void attn_mfma14(const ushort* __restrict__ Qe,
                                                   const ushort* __restrict__ Ke,
                                                   const ushort* __restrict__ Vt,
                                                   ushort* __restrict__ Ob) {
    __shared__ ushort Ks[64][128];       // swizzled K-ext tile [key][128]  16KB
    __shared__ ushort Vts[64][64];       // swizzled V^T tile [d][64key]     8KB
    __shared__ ushort PsT[8][16][64];    // swizzled per-wave P^T [q][64]   16KB

    const int tid = threadIdx.x;
    const int wave = tid >> 6, lane = tid & 63;
    const int col = lane & 15, quad = lane >> 4;

    // XCD-aware balanced decode (bijective over 512 ids)
    const int id = blockIdx.x;
    const int x = id & 7;                // XCD lane == bh&7
    const int k = id >> 3;               // 0..63
    const int rep = k & 1;
    const int bhi = (k >> 1) & 3;        // invariant under id -> id+256
    const int qh = k >> 3;               // 0..7; id+256 -> qh+4 (mod 8 range)
    const int bh = bhi * 8 + x;
    const int qt = rep ? (qh < 4 ? qh + 4 : 15 - qh)
                       : (qh < 4 ? qh : 19 - qh);
    const int b = bh >> 4, h = bh & 15;
    const int q0 = qt * ABQ;
    const int rowb = q0 + wave * 16;     // this wave's 16-row strip

    // Q fragments (K=128) for this wave's strip; MFMA B operand.
    short8 qf[4];
    {
        const ushort* qp = Qe + ((size_t)bh * Ss + rowb + col) * 128 + quad * 8;
#pragma unroll
        for (int k0 = 0; k0 < 4; ++k0) qf[k0] = *(const short8*)(qp + k0 * 32);
    }

    const f32x4 zero4 = {0.f, 0.f, 0.f, 0.f};
    f32x4 oaccT[4] = {zero4, zero4, zero4, zero4};
    float lsum = 0.f;                    // per-lane: q = rowb + col

    const ushort* Kbase = Ke + (size_t)bh * Ss * 128;
    const ushort* Vbase = Vt + (size_t)bh * 64 * Ss;
    const int xsw = col & 7;             // read-side swizzle

    // gload_lds staging: LDS granule h of row r = global granule h^(r&7).
    // K tile 64x16 granules (2 insts/thread), V tile 64x8 granules (1 inst).
    const int Gk0 = wave * 64 + lane;            // K inst 0: granules 0..511
    const int rk0 = Gk0 >> 4, sk0 = (Gk0 & 15) ^ (rk0 & 7);
    const int Gk1 = 512 + Gk0;                   // K inst 1: granules 512..1023
    const int rk1 = Gk1 >> 4, sk1 = (Gk1 & 15) ^ (rk1 & 7);
    const int Gv = Gk0;                          // V: granules 0..511
    const int rv = Gv >> 3, sv = (Gv & 7) ^ (rv & 7);
    const ushort* ksrc0 = Kbase + (size_t)rk0 * 128 + sk0 * 8;
    const ushort* ksrc1 = Kbase + (size_t)rk1 * 128 + sk1 * 8;
    const ushort* vsrc  = Vbase + (size_t)rv * Ss + sv * 8;
    ushort* kdst0 = &Ks[0][0] + wave * 512;              // wave-uniform bases
    ushort* kdst1 = &Ks[0][0] + 4096 + wave * 512;
    ushort* vdst  = &Vts[0][0] + wave * 512;

    const int ntiles = 2 * qt + 2;
    for (int t = 0; t < ntiles; ++t) {
        const int j0 = t * 64;
        __syncthreads();                 // prior tile's reads all done
        gload_lds16(ksrc0, kdst0);   ksrc0 += 64 * 128;
        gload_lds16(ksrc1, kdst1);   ksrc1 += 64 * 128;
        gload_lds16(vsrc,  vdst);    vsrc  += 64;
        __syncthreads();                 // vmcnt(0) drain: tile staged

        if (j0 > rowb + 15) continue;    // strip fully masked for this tile

        // S^T tiles: c tiles the KEY dim (4 x 16 keys), q = col
        f32x4 sacc[4] = {zero4, zero4, zero4, zero4};
        __builtin_amdgcn_s_setprio(1);
#pragma unroll
        for (int c = 0; c < 4; ++c)
#pragma unroll
            for (int k0 = 0; k0 < 4; ++k0) {
                short8 kf = *(const short8*)&Ks[c * 16 + col][((k0 * 4 + quad) ^ xsw) * 8];
                sacc[c] = __builtin_amdgcn_mfma_f32_16x16x32_bf16(kf, qf[k0], sacc[c], 0, 0, 0);
            }
        __builtin_amdgcn_s_setprio(0);

        const bool diag = (j0 + 63 >= rowb);     // tile crosses this strip's diagonal
        if (diag) {
            const int qrow_rel = rowb + col - j0;    // mask: key_rel > qrow_rel
#pragma unroll
            for (int c = 0; c < 4; ++c)
#pragma unroll
                for (int reg = 0; reg < 4; ++reg) {
                    float s = sacc[c][reg];
                    if (c * 16 + quad * 4 + reg > qrow_rel) s = -1e9f;
                    float p = fexp2(fminf(s, 28.853901f));
                    lsum += p;
                    sacc[c][reg] = p;
                }
        } else {
#pragma unroll
            for (int c = 0; c < 4; ++c)
#pragma unroll
                for (int reg = 0; reg < 4; ++reg) {
                    float p = fexp2(fminf(sacc[c][reg], 28.853901f));
                    lsum += p;
                    sacc[c][reg] = p;
                }
        }
#pragma unroll
        for (int c = 0; c < 4; ++c) {
            uint2 pk;
            pk.x = cvt_pk_bf16(sacc[c][0], sacc[c][1]);
            pk.y = cvt_pk_bf16(sacc[c][2], sacc[c][3]);
            *(uint2*)&PsT[wave][col][((c * 2 + (quad >> 1)) ^ xsw) * 8 + (quad & 1) * 4] = pk;
        }

        // PV: O^T += V^T (A) x P^T (B); per-wave LDS round-trip (DS in-order)
        __builtin_amdgcn_s_setprio(1);
#pragma unroll
        for (int k0 = 0; k0 < 2; ++k0) {
            short8 ptf = *(const short8*)&PsT[wave][col][((k0 * 4 + quad) ^ xsw) * 8];
#pragma unroll
            for (int c2 = 0; c2 < 4; ++c2) {
                short8 vtf = *(const short8*)&Vts[c2 * 16 + col][((k0 * 4 + quad) ^ xsw) * 8];
                oaccT[c2] = __builtin_amdgcn_mfma_f32_16x16x32_bf16(vtf, ptf, oaccT[c2], 0, 0, 0);
            }
        }
        __builtin_amdgcn_s_setprio(0);
    }

    // epilogue: O[q][d], q = rowb+col, d = c2*16 + quad*4 + reg
    {
        float l = lsum;
        l += __shfl_xor(l, 16, 64);
        l += __shfl_xor(l, 32, 64);              // sum over the 4 quads (same col)
        const float inv = 1.f / l;
        ushort* dst = Ob + ((size_t)b * Ss + rowb + col) * Dd + h * DK + quad * 4;
#pragma unroll
        for (int c2 = 0; c2 < 4; ++c2) {
            uint2 pk;
            pk.x = cvt_pk_bf16(oaccT[c2][0] * inv, oaccT[c2][1] * inv);
            pk.y = cvt_pk_bf16(oaccT[c2][2] * inv, oaccT[c2][3] * inv);
            *(uint2*)(dst + c2 * 16) = pk;
        }
    }
}

// ---------------------------------------------------------------------------
extern "C" void kernel_launch(void* const* d_in, const int* in_sizes, int n_in,
                              void* d_out, int out_size, void* d_ws, size_t ws_size,
                              hipStream_t stream) {
    const float* x            = (const float*)d_in[0];
    const float* features     = (const float*)d_in[1];
    const float* requirements = (const float*)d_in[2];
    const float* Wq = (const float*)d_in[3];
    const float* bq = (const float*)d_in[4];
    const float* Wk = (const float*)d_in[5];
    const float* bk = (const float*)d_in[6];
    const float* Wv = (const float*)d_in[7];
    const float* bv = (const float*)d_in[8];
    const float* Wo = (const float*)d_in[9];
    const float* bo = (const float*)d_in[10];

    float* out = (float*)d_out;
    float* ws = (float*)d_ws;

    // workspace layout (float offsets)
    ushort* xb   = (ushort*)(ws);                 // [4096,1024] bf16, 8MB
    ushort* WT   = (ushort*)(ws + 2097152);       // [4][1024][1024] bf16, 8MB
    ushort* Qext = (ushort*)(ws + 4194304);       // [32][2048][128] bf16, 16MB
    ushort* Kext = (ushort*)(ws + 8388608);       // 16MB
    ushort* Vt   = (ushort*)(ws + 16777216);      // [32][64][2048] bf16, 8MB
    ushort* abb  = (ushort*)(ws + 12582912);      // attn out bf16 (was Vrow slot)

    prep<<<10240, 256, 0, stream>>>(x, features, requirements, Wq, Wk, Wv, Wo,
                                    WT, xb, Qext, Kext);

    gemm_qkv<<<dim3(24, 32), 256, 0, stream>>>(xb, WT, bq, bk, bv, Qext, Kext, Vt);

    attn_mfma14<<<dim3(512), 512, 0, stream>>>(Qext, Kext, Vt, abb);

    gemm_out<<<dim3(8, 32), 512, 0, stream>>>(abb, WT + (size_t)3 * Dd * Dd, bo, out);
}

// Round 18
// 223.772 us; speedup vs baseline: 1.0147x; 1.0147x over previous
//
#include <hip/hip_runtime.h>
#include <hip/hip_bf16.h>
#include <math.h>

// Problem constants (reference: B,S,D,H,FD = 2,2048,1024,16,64; DK=64, ALPHA=1)
#define Bb 2
#define Ss 2048
#define Dd 1024
#define Hh 16
#define DK 64
#define FD 64

#define LOG2E 1.4426950408889634f

typedef short short8 __attribute__((ext_vector_type(8)));   // 8 bf16 (4 VGPRs)
typedef float f32x4 __attribute__((ext_vector_type(4)));
typedef unsigned int u32;

static __device__ inline ushort f2bf(float f) {
    union { float f; unsigned u; } v; v.f = f;
    unsigned r = v.u + 0x7FFF + ((v.u >> 16) & 1);   // round-to-nearest-even
    return (ushort)(r >> 16);
}

// packed f32x2 -> bf16x2 RNE in one VALU op
static __device__ inline uint cvt_pk_bf16(float lo, float hi) {
    uint r;
    asm("v_cvt_pk_bf16_f32 %0, %1, %2" : "=v"(r) : "v"(lo), "v"(hi));
    return r;
}
static __device__ inline float fexp2(float x) {
    return __builtin_amdgcn_exp2f(x);   // v_exp_f32: D = 2^S0
}

// async global->LDS, 16B per lane; LDS dest is wave-uniform base + lane*16
static __device__ inline void gload_lds16(const ushort* g, ushort* l) {
    __builtin_amdgcn_global_load_lds((const __attribute__((address_space(1))) u32*)g,
                                     (__attribute__((address_space(3))) u32*)l, 16, 0, 0);
}

// ---------------------------------------------------------------------------
// prep: fused cast_bf16 | transpose_cast4 | l2norm->COMPACT aux arrays.
// Aux is no longer replicated 16x per head: fnc/rnc are [B][S][64] bf16
// (0.5MB each, coalesced 128B-row writes); attn splices them into the K/Q
// ext layout at staging time (gload_lds global source is per-lane).
// ---------------------------------------------------------------------------
__global__ __launch_bounds__(256) void prep(const float* __restrict__ x,
                                            const float* __restrict__ features,
                                            const float* __restrict__ requirements,
                                            const float* __restrict__ W0,
                                            const float* __restrict__ W1,
                                            const float* __restrict__ W2,
                                            const float* __restrict__ W3,
                                            ushort* __restrict__ WT,
                                            ushort* __restrict__ xb,
                                            ushort* __restrict__ fnc,
                                            ushort* __restrict__ rnc) {
    __shared__ float T[64][65];
    const int blk = blockIdx.x;
    const int tid = threadIdx.x;

    if (blk < 8192) {
        // ---- cast fp32 -> bf16 (2 elems/thread) ----
        size_t p = (size_t)blk * 256 + tid;
        float2 v = *(const float2*)(x + 2 * p);
        ((uint*)xb)[p] = (uint)f2bf(v.x) | ((uint)f2bf(v.y) << 16);
        return;
    }
    if (blk < 9216) {
        // ---- transpose+cast weights (was dim3(16,16,4)) ----
        const int f = blk - 8192;
        const int bx = f & 15, by = (f >> 4) & 15, bz = f >> 8;
        const float* W = bz == 0 ? W0 : bz == 1 ? W1 : bz == 2 ? W2 : W3;
        ushort* dst = WT + (size_t)bz * Dd * Dd;
        const int k0 = bx * 64, n0 = by * 64;
#pragma unroll
        for (int i = 0; i < 4; ++i) {
            int kr = i * 16 + (tid >> 4);
            int nc = (tid & 15) * 4;
            float4 v = *(const float4*)(W + (size_t)(k0 + kr) * Dd + n0 + nc);
            T[kr][nc] = v.x; T[kr][nc + 1] = v.y; T[kr][nc + 2] = v.z; T[kr][nc + 3] = v.w;
        }
        __syncthreads();
        int nr = tid >> 2;
        int kc = (tid & 3) * 16;
        uint pk[8];
#pragma unroll
        for (int j = 0; j < 8; ++j)
            pk[j] = (uint)f2bf(T[kc + 2 * j][nr]) | ((uint)f2bf(T[kc + 2 * j + 1][nr]) << 16);
        uint* o = (uint*)(dst + (size_t)(n0 + nr) * Dd + k0 + kc);
        *(int4*)o = *(int4*)&pk[0];
        *(int4*)(o + 4) = *(int4*)&pk[4];
        return;
    }
    // ---- fused l2norm -> compact aux: 4 rows/block, wave per row ----
    {
        const int f3 = blk - 9216;               // 0..1023
        const int row = f3 * 4 + (tid >> 6);     // 0..4095 = b*S + s
        const int lane = tid & 63;
        // lanes 0-31: features -> fnc; lanes 32-63: requirements*log2e -> rnc
        const int j = lane & 31;
        const float* src = (lane < 32) ? features : requirements;
        float2 v = *(const float2*)(src + (size_t)row * FD + 2 * j);
        float ss = v.x * v.x + v.y * v.y;
#pragma unroll
        for (int off = 16; off; off >>= 1) ss += __shfl_xor(ss, off, 64);  // per-half
        const float inv = 1.0f / fmaxf(sqrtf(ss), 1e-12f);
        const float scl = (lane < 32) ? inv : inv * LOG2E;
        const uint pk = cvt_pk_bf16(v.x * scl, v.y * scl);
        if (lane < 32) ((uint*)fnc)[(size_t)row * 32 + j] = pk;
        else           ((uint*)rnc)[(size_t)row * 32 + j] = pk;
    }
}

// ---------------------------------------------------------------------------
// Fused QKV bf16 MFMA GEMM. 128x128 tile, BK=64, 4 waves.
// Round-15 VERIFIED body; Q/K epilogues now write COMPACT [bh][s][64] rows
// (identical code pattern to the verified Vrow/V^T writes).
// id0 -> Qm (x 0.125*log2e), id1 -> Km, id2 -> Vt (transposed).
// ---------------------------------------------------------------------------
__global__ __launch_bounds__(256) void gemm_qkv(const ushort* __restrict__ xb,
                                                const ushort* __restrict__ WT,
                                                const float* __restrict__ bq,
                                                const float* __restrict__ bk,
                                                const float* __restrict__ bv,
                                                ushort* __restrict__ Qm,
                                                ushort* __restrict__ Km,
                                                ushort* __restrict__ Vt) {
    __shared__ ushort smem[17408];        // 34.8KB: As|Bs (32KB) main, Ep epi
    ushort (*As)[64] = (ushort (*)[64])smem;            // [128][64]
    ushort (*Bs)[64] = (ushort (*)[64])(smem + 8192);   // [128][64]
    const int tid = threadIdx.x;
    const int lane = tid & 63, wave = tid >> 6;
    const int col = lane & 15, quad = lane >> 4;
    const int wm = wave >> 1, wn = wave & 1;
    // XCD swizzle (bijective): flat -> (id, n0=xcd*128, m0)
    const int flat = blockIdx.x + 24 * blockIdx.y;
    const int xcd = flat & 7;
    const int jj = flat >> 3;                     // 0..95
    const int id = jj % 3;                        // 0:Q 1:K 2:V
    const int n0 = xcd * 128;
    const int m0 = (jj / 3) * 128;
    const ushort* BTw = WT + (size_t)id * Dd * Dd;
    const float* bias = id == 0 ? bq : id == 1 ? bk : bv;

    const int l8 = lane >> 3;
    const int srcg = (lane & 7) ^ l8;             // r&7 == lane>>3
    const ushort* aS[4]; const ushort* bS[4];
    ushort* aD[4]; ushort* bD[4];
#pragma unroll
    for (int i = 0; i < 4; ++i) {
        int r = wave * 32 + i * 8 + l8;
        aS[i] = xb  + (size_t)(m0 + r) * Dd + srcg * 8;
        bS[i] = BTw + (size_t)(n0 + r) * Dd + srcg * 8;
        aD[i] = smem + (wave * 4 + i) * 512;
        bD[i] = smem + 8192 + (wave * 4 + i) * 512;
    }
    const int xs = col & 7;

    f32x4 acc[4][4] = {};

    for (int k0 = 0; k0 < Dd; k0 += 64) {
        __syncthreads();
#pragma unroll
        for (int i = 0; i < 4; ++i) {
            gload_lds16(aS[i] + k0, aD[i]);
            gload_lds16(bS[i] + k0, bD[i]);
        }
        __syncthreads();
#pragma unroll
        for (int kk = 0; kk < 2; ++kk) {
            short8 af[4], bf[4];
#pragma unroll
            for (int i = 0; i < 4; ++i) {
                af[i] = *(const short8*)&As[wm * 64 + i * 16 + col][((kk * 4 + quad) ^ xs) * 8];
                bf[i] = *(const short8*)&Bs[wn * 64 + i * 16 + col][((kk * 4 + quad) ^ xs) * 8];
            }
#pragma unroll
            for (int i = 0; i < 4; ++i)
#pragma unroll
                for (int j = 0; j < 4; ++j)
                    acc[i][j] = __builtin_amdgcn_mfma_f32_16x16x32_bf16(af[i], bf[j], acc[i][j], 0, 0, 0);
        }
    }

    // ---- coalesced epilogue via LDS (v8-verified, [136] padded) ----
    __syncthreads();                               // As/Bs reads all done
    ushort (*Ep)[136] = (ushort (*)[136])smem;     // 128x136 = 34.8KB
    const float scl = (id == 0) ? 0.125f * LOG2E : 1.0f;
#pragma unroll
    for (int j = 0; j < 4; ++j) {
        int n_local = wn * 64 + j * 16 + col;
        float bvl = bias[n0 + n_local];
#pragma unroll
        for (int i = 0; i < 4; ++i) {
            int mb = wm * 64 + i * 16 + quad * 4;
#pragma unroll
            for (int reg = 0; reg < 4; ++reg)
                Ep[mb + reg][n_local] = f2bf((acc[i][j][reg] + bvl) * scl);
        }
    }
    __syncthreads();
    if (id == 2) {
        // ---- fused V^T write: Vt[(b*Hh+hh)*64+d][s0 + 2*lane(+1)] ----
        const int b = m0 >> 11, s0 = m0 & (Ss - 1);
#pragma unroll
        for (int it = 0; it < 32; ++it) {
            int n_local = wave * 32 + it;        // waves 0-1: head 0; 2-3: head 1
            int hh = (n0 >> 6) + (n_local >> 6);
            int d = n_local & 63;
            uint pk = (uint)Ep[lane * 2][n_local] | ((uint)Ep[lane * 2 + 1][n_local] << 16);
            uint* dst = (uint*)(Vt + ((size_t)((b * Hh + hh) * DK + d)) * Ss + s0);
            dst[lane] = pk;                      // 64 lanes -> 256B coalesced
        }
    } else {
        const int mrow = tid >> 1;               // 0..127 local s
        const int half = tid & 1;                // which head of the 2 in n-range
        const int b = m0 >> 11, s = (m0 & (Ss - 1)) + mrow;
        const int hh = (n0 >> 6) + half;
        ushort* drow = (id == 0 ? Qm : Km) + ((size_t)(b * Hh + hh) * Ss + s) * 64;
#pragma unroll
        for (int k = 0; k < 8; ++k)
            *(int4*)(drow + k * 8) = *(int4*)&Ep[mrow][half * 64 + k * 8];
    }
}

// ---------------------------------------------------------------------------
// Output projection: out[M][N] f32 = abb(bf16) @ WoT + bo.
// Round-7/15 VERIFIED: 256 threads, gload_lds staging, swizzled reads.
// ---------------------------------------------------------------------------
__global__ __launch_bounds__(256) void gemm_out(const ushort* __restrict__ Ab,
                                                const ushort* __restrict__ BT,
                                                const float* __restrict__ bias,
                                                float* __restrict__ C) {
    __shared__ ushort As[128][64];
    __shared__ ushort Bs[128][64];
    const int tid = threadIdx.x;
    const int lane = tid & 63, wave = tid >> 6;
    const int col = lane & 15, quad = lane >> 4;
    const int wm = wave >> 1, wn = wave & 1;
    const int n0 = blockIdx.x * 128;
    const int m0 = blockIdx.y * 128;

    const int l8 = lane >> 3;
    const int srcg = (lane & 7) ^ l8;             // r&7 == lane>>3
    const ushort* aS[4]; const ushort* bS[4];
    ushort* aD[4]; ushort* bD[4];
#pragma unroll
    for (int i = 0; i < 4; ++i) {
        int r = wave * 32 + i * 8 + l8;
        aS[i] = Ab + (size_t)(m0 + r) * Dd + srcg * 8;
        bS[i] = BT + (size_t)(n0 + r) * Dd + srcg * 8;
        aD[i] = &As[0][0] + (wave * 4 + i) * 512;
        bD[i] = &Bs[0][0] + (wave * 4 + i) * 512;
    }
    const int xs = col & 7;

    f32x4 acc[4][4] = {};

    for (int k0 = 0; k0 < Dd; k0 += 64) {
        __syncthreads();
#pragma unroll
        for (int i = 0; i < 4; ++i) {
            gload_lds16(aS[i] + k0, aD[i]);
            gload_lds16(bS[i] + k0, bD[i]);
        }
        __syncthreads();
#pragma unroll
        for (int kk = 0; kk < 2; ++kk) {
            short8 af[4], bf[4];
#pragma unroll
            for (int i = 0; i < 4; ++i) {
                af[i] = *(const short8*)&As[wm * 64 + i * 16 + col][((kk * 4 + quad) ^ xs) * 8];
                bf[i] = *(const short8*)&Bs[wn * 64 + i * 16 + col][((kk * 4 + quad) ^ xs) * 8];
            }
#pragma unroll
            for (int i = 0; i < 4; ++i)
#pragma unroll
                for (int j = 0; j < 4; ++j)
                    acc[i][j] = __builtin_amdgcn_mfma_f32_16x16x32_bf16(af[i], bf[j], acc[i][j], 0, 0, 0);
        }
    }

#pragma unroll
    for (int j = 0; j < 4; ++j) {
        int n = n0 + wn * 64 + j * 16 + col;
        float bvl = bias[n];
#pragma unroll
        for (int i = 0; i < 4; ++i) {
#pragma unroll
            for (int reg = 0; reg < 4; ++reg) {
                int m = m0 + wm * 64 + i * 16 + quad * 4 + reg;
                C[(size_t)m * Dd + n] = acc[i][j][reg] + bvl;
            }
        }
    }
}

// ---------------------------------------------------------------------------
// Flash attention v16 = v14 (round-11/14/15 verified body) with COMPACT
// aux splicing: K tiles stage main (Km) + aux (fnc, shared across heads,
// L2-hot) via per-lane source base select — bit 3 of the swizzled slot is
// XOR-invariant, so lanes with slot bit 3 set source aux. LDS contents,
// reads, barriers all bit-identical to v14. Q frags read Qm + rnc directly.
// ---------------------------------------------------------------------------
#define ABQ 128

__global__ __launch_bounds__(512) void attn_mfma16(const ushort* __restrict__ Qm,
                                                   const ushort* __restrict__ Km,
                                                   const ushort* __restrict__ fnc,
                                                   const ushort* __restrict__ rnc,
                                                   const ushort* __restrict__ Vt,
                                                   ushort* __restrict__ Ob) {
    __shared__ ushort Ks[64][128];       // swizzled K-ext tile [key][128]  16KB
    __shared__ ushort Vts[64][64];       // swizzled V^T tile [d][64key]     8KB
    __shared__ ushort PsT[8][16][64];    // swizzled per-wave P^T [q][64]   16KB

    const int tid = threadIdx.x;
    const int wave = tid >> 6, lane = tid & 63;
    const int col = lane & 15, quad = lane >> 4;

    // XCD-aware balanced decode (bijective over 512 ids)
    const int id = blockIdx.x;
    const int x = id & 7;                // XCD lane == bh&7
    const int k = id >> 3;               // 0..63
    const int rep = k & 1;
    const int bhi = (k >> 1) & 3;        // invariant under id -> id+256
    const int qh = k >> 3;               // 0..7; id+256 -> qh+4 (mod 8 range)
    const int bh = bhi * 8 + x;
    const int qt = rep ? (qh < 4 ? qh + 4 : 15 - qh)
                       : (qh < 4 ? qh : 19 - qh);
    const int b = bh >> 4, h = bh & 15;
    const int q0 = qt * ABQ;
    const int rowb = q0 + wave * 16;     // this wave's 16-row strip

    // Q fragments (K=128): main from Qm, aux from rnc (pre-scaled x log2e).
    short8 qf[4];
    {
        const ushort* qpm = Qm + ((size_t)bh * Ss + rowb + col) * 64 + quad * 8;
        const ushort* qpa = rnc + ((size_t)(b * Ss) + rowb + col) * 64 + quad * 8;
        qf[0] = *(const short8*)qpm;
        qf[1] = *(const short8*)(qpm + 32);
        qf[2] = *(const short8*)qpa;
        qf[3] = *(const short8*)(qpa + 32);
    }

    const f32x4 zero4 = {0.f, 0.f, 0.f, 0.f};
    f32x4 oaccT[4] = {zero4, zero4, zero4, zero4};
    float lsum = 0.f;                    // per-lane: q = rowb + col

    const ushort* Kbase = Km + (size_t)bh * Ss * 64;
    const ushort* Abase = fnc + (size_t)b * Ss * 64;
    const ushort* Vbase = Vt + (size_t)bh * 64 * Ss;
    const int xsw = col & 7;             // read-side swizzle

    // gload_lds staging: LDS slot h of row r = ext granule h^(r&7), where
    // ext row = [Km row (8 granules) | fnc row (8 granules)]. Bit 3 of the
    // swizzled slot is XOR-invariant -> selects base. Both advance 4096/tile.
    const int Gk0 = wave * 64 + lane;            // K inst 0: granules 0..511
    const int rk0 = Gk0 >> 4, sk0 = (Gk0 & 15) ^ (rk0 & 7);
    const int Gk1 = 512 + Gk0;                   // K inst 1: granules 512..1023
    const int rk1 = Gk1 >> 4, sk1 = (Gk1 & 15) ^ (rk1 & 7);
    const int Gv = Gk0;                          // V: granules 0..511
    const int rv = Gv >> 3, sv = (Gv & 7) ^ (rv & 7);
    const ushort* ksrc0 = (sk0 < 8 ? Kbase + (size_t)rk0 * 64 + sk0 * 8
                                   : Abase + (size_t)rk0 * 64 + (sk0 - 8) * 8);
    const ushort* ksrc1 = (sk1 < 8 ? Kbase + (size_t)rk1 * 64 + sk1 * 8
                                   : Abase + (size_t)rk1 * 64 + (sk1 - 8) * 8);
    const ushort* vsrc  = Vbase + (size_t)rv * Ss + sv * 8;
    ushort* kdst0 = &Ks[0][0] + wave * 512;              // wave-uniform bases
    ushort* kdst1 = &Ks[0][0] + 4096 + wave * 512;
    ushort* vdst  = &Vts[0][0] + wave * 512;

    const int ntiles = 2 * qt + 2;
    for (int t = 0; t < ntiles; ++t) {
        const int j0 = t * 64;
        __syncthreads();                 // prior tile's reads all done
        gload_lds16(ksrc0, kdst0);   ksrc0 += 64 * 64;
        gload_lds16(ksrc1, kdst1);   ksrc1 += 64 * 64;
        gload_lds16(vsrc,  vdst);    vsrc  += 64;
        __syncthreads();                 // vmcnt(0) drain: tile staged

        if (j0 > rowb + 15) continue;    // strip fully masked for this tile

        // S^T tiles: c tiles the KEY dim (4 x 16 keys), q = col
        f32x4 sacc[4] = {zero4, zero4, zero4, zero4};
        __builtin_amdgcn_s_setprio(1);
#pragma unroll
        for (int c = 0; c < 4; ++c)
#pragma unroll
            for (int k0 = 0; k0 < 4; ++k0) {
                short8 kf = *(const short8*)&Ks[c * 16 + col][((k0 * 4 + quad) ^ xsw) * 8];
                sacc[c] = __builtin_amdgcn_mfma_f32_16x16x32_bf16(kf, qf[k0], sacc[c], 0, 0, 0);
            }
        __builtin_amdgcn_s_setprio(0);

        const bool diag = (j0 + 63 >= rowb);     // tile crosses this strip's diagonal
        if (diag) {
            const int qrow_rel = rowb + col - j0;    // mask: key_rel > qrow_rel
#pragma unroll
            for (int c = 0; c < 4; ++c)
#pragma unroll
                for (int reg = 0; reg < 4; ++reg) {
                    float s = sacc[c][reg];
                    if (c * 16 + quad * 4 + reg > qrow_rel) s = -1e9f;
                    float p = fexp2(fminf(s, 28.853901f));
                    lsum += p;
                    sacc[c][reg] = p;
                }
        } else {
#pragma unroll
            for (int c = 0; c < 4; ++c)
#pragma unroll
                for (int reg = 0; reg < 4; ++reg) {
                    float p = fexp2(fminf(sacc[c][reg], 28.853901f));
                    lsum += p;
                    sacc[c][reg] = p;
                }
        }
#pragma unroll
        for (int c = 0; c < 4; ++c) {
            uint2 pk;
            pk.x = cvt_pk_bf16(sacc[c][0], sacc[c][1]);
            pk.y = cvt_pk_bf16(sacc[c][2], sacc[c][3]);
            *(uint2*)&PsT[wave][col][((c * 2 + (quad >> 1)) ^ xsw) * 8 + (quad & 1) * 4] = pk;
        }

        // PV: O^T += V^T (A) x P^T (B); per-wave LDS round-trip (DS in-order)
        __builtin_amdgcn_s_setprio(1);
#pragma unroll
        for (int k0 = 0; k0 < 2; ++k0) {
            short8 ptf = *(const short8*)&PsT[wave][col][((k0 * 4 + quad) ^ xsw) * 8];
#pragma unroll
            for (int c2 = 0; c2 < 4; ++c2) {
                short8 vtf = *(const short8*)&Vts[c2 * 16 + col][((k0 * 4 + quad) ^ xsw) * 8];
                oaccT[c2] = __builtin_amdgcn_mfma_f32_16x16x32_bf16(vtf, ptf, oaccT[c2], 0, 0, 0);
            }
        }
        __builtin_amdgcn_s_setprio(0);
    }

    // epilogue: O[q][d], q = rowb+col, d = c2*16 + quad*4 + reg
    {
        float l = lsum;
        l += __shfl_xor(l, 16, 64);
        l += __shfl_xor(l, 32, 64);              // sum over the 4 quads (same col)
        const float inv = 1.f / l;
        ushort* dst = Ob + ((size_t)b * Ss + rowb + col) * Dd + h * DK + quad * 4;
#pragma unroll
        for (int c2 = 0; c2 < 4; ++c2) {
            uint2 pk;
            pk.x = cvt_pk_bf16(oaccT[c2][0] * inv, oaccT[c2][1] * inv);
            pk.y = cvt_pk_bf16(oaccT[c2][2] * inv, oaccT[c2][3] * inv);
            *(uint2*)(dst + c2 * 16) = pk;
        }
    }
}

// ---------------------------------------------------------------------------
extern "C" void kernel_launch(void* const* d_in, const int* in_sizes, int n_in,
                              void* d_out, int out_size, void* d_ws, size_t ws_size,
                              hipStream_t stream) {
    const float* x            = (const float*)d_in[0];
    const float* features     = (const float*)d_in[1];
    const float* requirements = (const float*)d_in[2];
    const float* Wq = (const float*)d_in[3];
    const float* bq = (const float*)d_in[4];
    const float* Wk = (const float*)d_in[5];
    const float* bk = (const float*)d_in[6];
    const float* Wv = (const float*)d_in[7];
    const float* bv = (const float*)d_in[8];
    const float* Wo = (const float*)d_in[9];
    const float* bo = (const float*)d_in[10];

    float* out = (float*)d_out;
    float* ws = (float*)d_ws;

    // workspace layout (float offsets)
    ushort* xb   = (ushort*)(ws);                 // [4096,1024] bf16, 8MB
    ushort* WT   = (ushort*)(ws + 2097152);       // [4][1024][1024] bf16, 8MB
    ushort* Qm   = (ushort*)(ws + 4194304);       // [32][2048][64] bf16, 8MB
    ushort* Km   = (ushort*)(ws + 6291456);       // 8MB
    ushort* Vt   = (ushort*)(ws + 8388608);       // [32][64][2048] bf16, 8MB
    ushort* abb  = (ushort*)(ws + 10485760);      // attn out bf16, 8MB
    ushort* fnc  = (ushort*)(ws + 12582912);      // [2][2048][64] bf16, 0.5MB
    ushort* rnc  = (ushort*)(ws + 12713984);      // 0.5MB

    prep<<<10240, 256, 0, stream>>>(x, features, requirements, Wq, Wk, Wv, Wo,
                                    WT, xb, fnc, rnc);

    gemm_qkv<<<dim3(24, 32), 256, 0, stream>>>(xb, WT, bq, bk, bv, Qm, Km, Vt);

    attn_mfma16<<<dim3(512), 512, 0, stream>>>(Qm, Km, fnc, rnc, Vt, abb);

    gemm_out<<<dim3(8, 32), 256, 0, stream>>>(abb, WT + (size_t)3 * Dd * Dd, bo, out);
}